// Round 1
// baseline (436.705 us; speedup 1.0000x reference)
//
#include <hip/hip_runtime.h>

#define E_EDGES 100000
#define NNODES  50000

// ---- workspace layout (in floats) ----
#define WS_AT   0        // A^T  [128][256]: qk[c] = sum_h At[h][c]*ea[h]
#define WS_WF   32768    // Wf   [256][128]: local_out[h] = sum_c mixed[c]*Wf[c][h]
#define WS_A0   65536    // a0   [256]
#define WS_U    65792    // u    [128]
#define WS_BF   65920    // bf   [128]
#define WS_C0   66048    // c0   [1]
#define WS_MG   66052    // M_g  [4][128]
#define WS_CG   66564    // c_g  [4]
#define WS_VOG  66568    // Vo_g [4][128]
#define WS_PART 67584    // pooled partials [256][512]

#define POOL_BLOCKS 256
#define POOL_ROWS   196

#define OUT_POOL ((size_t)E_EDGES * 384)
#define OUT_GAW  (OUT_POOL + 512)

static constexpr float SCALE = 0.08838834764831845f; // 1/sqrt(128)

// ---------- pooled_global partial sums: [256 blocks][512 cols] ----------
__global__ void k_pool_partial(const float* __restrict__ gf, float* __restrict__ part) {
    int t = threadIdx.x, b = blockIdx.x;
    int n0 = b * POOL_ROWS;
    int n1 = min(NNODES, n0 + POOL_ROWS);
    float s0 = 0.f, s1 = 0.f;
    for (int n = n0; n < n1; ++n) {
        s0 += gf[(size_t)n * 512 + t];
        s1 += gf[(size_t)n * 512 + 256 + t];
    }
    part[b * 512 + t]       = s0;
    part[b * 512 + 256 + t] = s1;
}

// ---------- fused local weights: A^T, Wf, a0, u, bf, c0 ----------
__global__ void k_prep_w(const float* __restrict__ wq_l, const float* __restrict__ wk_l,
                         const float* __restrict__ wv_l, const float* __restrict__ bq_l,
                         const float* __restrict__ bk_l, const float* __restrict__ bv_l,
                         const float* __restrict__ wo_l, const float* __restrict__ bo_l,
                         float* __restrict__ ws) {
    int id = blockIdx.x * 256 + threadIdx.x;
    if (id < 32768) {                      // At[h][c] = sum_m wk_l[m,c]*wq_l[m,h]
        int h = id >> 8, c = id & 255;
        float s = 0.f;
        for (int m = 0; m < 128; ++m) s = fmaf(wk_l[m * 256 + c], wq_l[m * 128 + h], s);
        ws[WS_AT + h * 256 + c] = s;
    } else if (id < 65536) {               // Wf[c][h] = sum_m wv_l[m,c]*wo_l[h,m]
        int id2 = id - 32768;
        int c = id2 >> 7, h = id2 & 127;
        float s = 0.f;
        for (int m = 0; m < 128; ++m) s = fmaf(wv_l[m * 256 + c], wo_l[h * 128 + m], s);
        ws[WS_WF + c * 128 + h] = s;
    } else if (id < 65792) {               // a0[c] = sum_m wk_l[m,c]*bq_l[m]
        int c = id - 65536;
        float s = 0.f;
        for (int m = 0; m < 128; ++m) s = fmaf(wk_l[m * 256 + c], bq_l[m], s);
        ws[WS_A0 + c] = s;
    } else if (id < 65920) {               // u[h] = sum_m bk_l[m]*wq_l[m,h]
        int h = id - 65792;
        float s = 0.f;
        for (int m = 0; m < 128; ++m) s = fmaf(bk_l[m], wq_l[m * 128 + h], s);
        ws[WS_U + h] = s;
    } else if (id < 66048) {               // bf[h] = sum_m bv_l[m]*wo_l[h,m] + bo_l[h]
        int h = id - 65920;
        float s = bo_l[h];
        for (int m = 0; m < 128; ++m) s = fmaf(bv_l[m], wo_l[h * 128 + m], s);
        ws[WS_BF + h] = s;
    } else if (id == 66048) {              // c0 = bq_l . bk_l
        float s = 0.f;
        for (int m = 0; m < 128; ++m) s = fmaf(bq_l[m], bk_l[m], s);
        ws[WS_C0] = s;
    }
}

// ---------- finish pooled mean; derive k_g,v_g -> M_g, c_g, Vo_g ----------
__global__ void k_pool_finish(const float* __restrict__ part,
                              const float* __restrict__ wk_g, const float* __restrict__ wv_g,
                              const float* __restrict__ wq_g, const float* __restrict__ bk_g,
                              const float* __restrict__ bv_g, const float* __restrict__ bq_g,
                              const float* __restrict__ wo_g,
                              float* __restrict__ out_pool, float* __restrict__ ws) {
    __shared__ float pooled[512], kg[512], vg[512];
    int t = threadIdx.x; // 512 threads
    float s = 0.f;
    for (int p = 0; p < POOL_BLOCKS; ++p) s += part[p * 512 + t];
    s *= (1.0f / 50000.0f);
    pooled[t]   = s;
    out_pool[t] = s;           // pooled_global is output #1
    __syncthreads();
    int j = t >> 7, m = t & 127;
    float k = bk_g[m], v = bv_g[m];
    for (int h = 0; h < 128; ++h) {
        float p = pooled[j * 128 + h];
        k = fmaf(p, wk_g[m * 128 + h], k);
        v = fmaf(p, wv_g[m * 128 + h], v);
    }
    kg[t] = k; vg[t] = v;
    __syncthreads();
    {   // M_g[j][h2] = sum_m wq_g[m,h2]*kg[j,m];  Vo_g[j][h2] = sum_m vg[j,m]*wo_g[h2,m]
        int h2 = t & 127;
        float s2 = 0.f, s3 = 0.f;
        for (int mm = 0; mm < 128; ++mm) {
            s2 = fmaf(wq_g[mm * 128 + h2], kg[j * 128 + mm], s2);
            s3 = fmaf(vg[j * 128 + mm], wo_g[h2 * 128 + mm], s3);
        }
        ws[WS_MG + t]  = s2;
        ws[WS_VOG + t] = s3;
    }
    if (t < 4) {
        float s4 = 0.f;
        for (int mm = 0; mm < 128; ++mm) s4 = fmaf(bq_g[mm], kg[t * 128 + mm], s4);
        ws[WS_CG + t] = s4;
    }
}

// ---------- main fused edge kernel: 32 edges / block, 256 threads ----------
__global__ __launch_bounds__(256)
void k_main(const float* __restrict__ ea, const float* __restrict__ gf,
            const int* __restrict__ eidx, const float* __restrict__ bo_g,
            const float* __restrict__ ws, float* __restrict__ out) {
    __shared__ float lds_ea[32][128];
    __shared__ float lds_qk[32][256];
    __shared__ float lds_Mg[512], lds_Vog[512];
    __shared__ float lds_u[128], lds_bf[128], lds_bog[128];
    __shared__ float lds_cg[4], lds_c0[1];

    int t  = threadIdx.x;
    int e0 = blockIdx.x * 32;

    {   // stage 32x128 edge_attr tile (contiguous) as float4
        const float4* src = (const float4*)(ea + (size_t)e0 * 128);
        float4* dst = (float4*)&lds_ea[0][0];
        #pragma unroll
        for (int i = 0; i < 4; ++i) dst[t + i * 256] = src[t + i * 256];
    }
    for (int i = t; i < 512; i += 256) { lds_Mg[i] = ws[WS_MG + i]; lds_Vog[i] = ws[WS_VOG + i]; }
    if (t < 128) { lds_u[t] = ws[WS_U + t]; lds_bf[t] = ws[WS_BF + t]; lds_bog[t] = bo_g[t]; }
    if (t < 4)  lds_cg[t] = ws[WS_CG + t];
    if (t == 0) lds_c0[0] = ws[WS_C0];
    __syncthreads();

    int c0 = t & 63;   // column / lane id
    int g  = t >> 6;   // wave id -> edge group (8 edges)

    // ---- phase 2: qk[e][c] = At@ea + a0, for this block's 32 edges ----
    {
        float acc[4][8];
        #pragma unroll
        for (int k = 0; k < 4; ++k)
            #pragma unroll
            for (int e = 0; e < 8; ++e) acc[k][e] = 0.f;
        const float* At = ws + WS_AT;
        #pragma unroll 4
        for (int h = 0; h < 128; ++h) {
            float w0 = At[h * 256 + c0];
            float w1 = At[h * 256 + 64 + c0];
            float w2 = At[h * 256 + 128 + c0];
            float w3 = At[h * 256 + 192 + c0];
            #pragma unroll
            for (int e = 0; e < 8; ++e) {
                float a = lds_ea[g * 8 + e][h];
                acc[0][e] = fmaf(w0, a, acc[0][e]);
                acc[1][e] = fmaf(w1, a, acc[1][e]);
                acc[2][e] = fmaf(w2, a, acc[2][e]);
                acc[3][e] = fmaf(w3, a, acc[3][e]);
            }
        }
        #pragma unroll
        for (int k = 0; k < 4; ++k) {
            float a0v = ws[WS_A0 + k * 64 + c0];
            #pragma unroll
            for (int e = 0; e < 8; ++e) lds_qk[g * 8 + e][k * 64 + c0] = acc[k][e] + a0v;
        }
    }
    __syncthreads();

    // ---- middle: per-wave, 8 edges: gather, scores, softmax, mix, global branch ----
    {
        int lane = c0;
        for (int ee = 0; ee < 8; ++ee) {
            int eL = g * 8 + ee;
            int eG = e0 + eL;
            int i0 = eidx[eG], i1 = eidx[E_EDGES + eG];
            const float* ps = gf + (size_t)i0 * 512;
            const float* pd = gf + (size_t)i1 * 512;
            float sa[4], sb[4], da[4], db[4];
            #pragma unroll
            for (int s = 0; s < 4; ++s) {
                sa[s] = ps[s * 128 + lane];      sb[s] = ps[s * 128 + 64 + lane];
                da[s] = pd[s * 128 + lane];      db[s] = pd[s * 128 + 64 + lane];
            }
            float q0 = lds_qk[eL][lane],        q1 = lds_qk[eL][64 + lane];
            float q2 = lds_qk[eL][128 + lane],  q3 = lds_qk[eL][192 + lane];
            float eaA = lds_ea[eL][lane], eaB = lds_ea[eL][64 + lane];
            float pb = eaA * lds_u[lane] + eaB * lds_u[64 + lane];
            float part[4], pg[4];
            #pragma unroll
            for (int s = 0; s < 4; ++s)
                part[s] = sa[s] * q0 + sb[s] * q1 + da[s] * q2 + db[s] * q3 + pb;
            #pragma unroll
            for (int jj = 0; jj < 4; ++jj)
                pg[jj] = eaA * lds_Mg[jj * 128 + lane] + eaB * lds_Mg[jj * 128 + 64 + lane];
            #pragma unroll
            for (int off = 32; off; off >>= 1) {
                #pragma unroll
                for (int s = 0; s < 4; ++s) {
                    part[s] += __shfl_xor(part[s], off, 64);
                    pg[s]   += __shfl_xor(pg[s],   off, 64);
                }
            }
            float c0v = lds_c0[0];
            float t0 = (part[0] + c0v) * SCALE, t1 = (part[1] + c0v) * SCALE;
            float t2 = (part[2] + c0v) * SCALE, t3 = (part[3] + c0v) * SCALE;
            float mx = fmaxf(fmaxf(t0, t1), fmaxf(t2, t3));
            float x0 = __expf(t0 - mx), x1 = __expf(t1 - mx);
            float x2 = __expf(t2 - mx), x3 = __expf(t3 - mx);
            float inv = 1.0f / (x0 + x1 + x2 + x3);
            float a0s = x0 * inv, a1s = x1 * inv, a2s = x2 * inv, a3s = x3 * inv;

            float g0 = (pg[0] + lds_cg[0]) * SCALE, g1 = (pg[1] + lds_cg[1]) * SCALE;
            float g2 = (pg[2] + lds_cg[2]) * SCALE, g3 = (pg[3] + lds_cg[3]) * SCALE;
            float mg = fmaxf(fmaxf(g0, g1), fmaxf(g2, g3));
            float y0 = __expf(g0 - mg), y1 = __expf(g1 - mg);
            float y2 = __expf(g2 - mg), y3 = __expf(g3 - mg);
            float invg = 1.0f / (y0 + y1 + y2 + y3);
            float b0 = y0 * invg, b1 = y1 * invg, b2 = y2 * invg, b3 = y3 * invg;

            if (lane < 4)
                out[OUT_GAW + (size_t)eG * 4 + lane] =
                    (lane == 0) ? b0 : (lane == 1) ? b1 : (lane == 2) ? b2 : b3;

            float go0 = lds_bog[lane]      + b0 * lds_Vog[lane]        + b1 * lds_Vog[128 + lane]
                                           + b2 * lds_Vog[256 + lane]  + b3 * lds_Vog[384 + lane];
            float go1 = lds_bog[64 + lane] + b0 * lds_Vog[64 + lane]   + b1 * lds_Vog[192 + lane]
                                           + b2 * lds_Vog[320 + lane]  + b3 * lds_Vog[448 + lane];
            size_t ro = (size_t)eG * 384;
            out[ro + 256 + lane] = go0;
            out[ro + 320 + lane] = go1;
            out[ro + lane]       = eaA;   // passthrough copy of edge_attr
            out[ro + 64 + lane]  = eaB;

            // overwrite qk row with mixed_lf (only this wave touches this row)
            lds_qk[eL][lane]        = a0s * sa[0] + a1s * sa[1] + a2s * sa[2] + a3s * sa[3];
            lds_qk[eL][64 + lane]   = a0s * sb[0] + a1s * sb[1] + a2s * sb[2] + a3s * sb[3];
            lds_qk[eL][128 + lane]  = a0s * da[0] + a1s * da[1] + a2s * da[2] + a3s * da[3];
            lds_qk[eL][192 + lane]  = a0s * db[0] + a1s * db[1] + a2s * db[2] + a3s * db[3];
        }
    }
    __syncthreads();

    // ---- phase 3: local_out = mixed @ Wf + bf ----
    {
        float acc[2][8];
        #pragma unroll
        for (int k = 0; k < 2; ++k)
            #pragma unroll
            for (int e = 0; e < 8; ++e) acc[k][e] = 0.f;
        const float* Wf = ws + WS_WF;
        #pragma unroll 4
        for (int c = 0; c < 256; ++c) {
            float w0 = Wf[c * 128 + c0];
            float w1 = Wf[c * 128 + 64 + c0];
            #pragma unroll
            for (int e = 0; e < 8; ++e) {
                float mv = lds_qk[g * 8 + e][c];
                acc[0][e] = fmaf(w0, mv, acc[0][e]);
                acc[1][e] = fmaf(w1, mv, acc[1][e]);
            }
        }
        float bf0 = lds_bf[c0], bf1 = lds_bf[64 + c0];
        #pragma unroll
        for (int e = 0; e < 8; ++e) {
            size_t ro = (size_t)(e0 + g * 8 + e) * 384;
            out[ro + 128 + c0] = acc[0][e] + bf0;
            out[ro + 192 + c0] = acc[1][e] + bf1;
        }
    }
}

extern "C" void kernel_launch(void* const* d_in, const int* in_sizes, int n_in,
                              void* d_out, int out_size, void* d_ws, size_t ws_size,
                              hipStream_t stream) {
    const float* edge_attr = (const float*)d_in[0];
    const float* gf        = (const float*)d_in[1];
    const int*   eidx      = (const int*)d_in[2];
    const float* wq_l = (const float*)d_in[3];
    const float* wk_l = (const float*)d_in[4];
    const float* wv_l = (const float*)d_in[5];
    const float* bq_l = (const float*)d_in[6];
    const float* bk_l = (const float*)d_in[7];
    const float* bv_l = (const float*)d_in[8];
    const float* wo_l = (const float*)d_in[9];
    const float* bo_l = (const float*)d_in[10];
    const float* wq_g = (const float*)d_in[11];
    const float* wk_g = (const float*)d_in[12];
    const float* wv_g = (const float*)d_in[13];
    const float* bq_g = (const float*)d_in[14];
    const float* bk_g = (const float*)d_in[15];
    const float* bv_g = (const float*)d_in[16];
    const float* wo_g = (const float*)d_in[17];
    const float* bo_g = (const float*)d_in[18];

    float* out = (float*)d_out;
    float* ws  = (float*)d_ws;

    k_pool_partial<<<POOL_BLOCKS, 256, 0, stream>>>(gf, ws + WS_PART);
    k_prep_w<<<259, 256, 0, stream>>>(wq_l, wk_l, wv_l, bq_l, bk_l, bv_l, wo_l, bo_l, ws);
    k_pool_finish<<<1, 512, 0, stream>>>(ws + WS_PART, wk_g, wv_g, wq_g, bk_g, bv_g, bq_g, wo_g,
                                         out + OUT_POOL, ws);
    k_main<<<E_EDGES / 32, 256, 0, stream>>>(edge_attr, gf, eidx, bo_g, ws, out);
}

// Round 3
// 179.874 us; speedup vs baseline: 2.4278x; 2.4278x over previous
//
#include <hip/hip_runtime.h>

typedef short short8 __attribute__((ext_vector_type(8)));
typedef float f32x4 __attribute__((ext_vector_type(4)));
typedef unsigned short u16;
typedef unsigned int u32;

#define E_EDGES 100000
#define NNODES  50000

// ---- workspace layout (in floats) ----
#define WS_ATPK 0        // At bf16 packed [h/8][c][h%8]  : 32768 u16 = 16384 floats
#define WS_WFPK 16384    // Wf bf16 packed [c/8][h][c%8]  : 32768 u16
#define WS_A0   32768    // a0 [256] fp32
#define WS_U    33024    // u  [128]
#define WS_BF   33152    // bf [128]
#define WS_C0   33280    // c0 [1]
#define WS_MG   33284    // M_g [4][128]
#define WS_CG   33796    // c_g [4]
#define WS_VOG  33800    // Vo_g [4][128]
#define WS_PART 34816    // pooled partials [256][512]

#define POOL_BLOCKS 256
#define POOL_ROWS   196

#define OUT_POOL ((size_t)E_EDGES * 384)
#define OUT_GAW  (OUT_POOL + 512)

static constexpr float SCALE = 0.08838834764831845f; // 1/sqrt(128)

__device__ __forceinline__ u16 f2bf(float x) {            // RNE fp32->bf16
    u32 u = __float_as_uint(x);
    u += 0x7fffu + ((u >> 16) & 1u);
    return (u16)(u >> 16);
}
__device__ __forceinline__ float bf2f(u16 h) { return __uint_as_float(((u32)h) << 16); }

// ---------- pooled_global partial sums ----------
__global__ void k_pool_partial(const float* __restrict__ gf, float* __restrict__ part) {
    __shared__ float4 sh[128];
    int t = threadIdx.x, b = blockIdx.x;
    int c4 = (t & 127) * 4;
    int half = t >> 7;
    int n1 = min(NNODES, b * POOL_ROWS + POOL_ROWS);
    float4 acc = {0.f, 0.f, 0.f, 0.f};
    #pragma unroll 4
    for (int n = b * POOL_ROWS + half; n < n1; n += 2) {
        float4 v = *(const float4*)(gf + (size_t)n * 512 + c4);
        acc.x += v.x; acc.y += v.y; acc.z += v.z; acc.w += v.w;
    }
    if (half) sh[t & 127] = acc;
    __syncthreads();
    if (!half) {
        float4 o = sh[t];
        acc.x += o.x; acc.y += o.y; acc.z += o.z; acc.w += o.w;
        *(float4*)(part + b * 512 + c4) = acc;
    }
}

// ---------- fused local weights: At(bf16 packed), Wf(bf16 packed), a0, u, bf, c0 ----------
__global__ void k_prep_w(const float* __restrict__ wq_l, const float* __restrict__ wk_l,
                         const float* __restrict__ wv_l, const float* __restrict__ bq_l,
                         const float* __restrict__ bk_l, const float* __restrict__ bv_l,
                         const float* __restrict__ wo_l, const float* __restrict__ bo_l,
                         float* __restrict__ ws) {
    u16* atpk = (u16*)(ws + WS_ATPK);
    u16* wfpk = (u16*)(ws + WS_WFPK);
    int id = blockIdx.x * 256 + threadIdx.x;
    if (id < 32768) {                      // At[h][c] = sum_m wk_l[m,c]*wq_l[m,h]
        int h = id >> 8, c = id & 255;
        float s = 0.f;
        for (int m = 0; m < 128; ++m) s = fmaf(wk_l[m * 256 + c], wq_l[m * 128 + h], s);
        atpk[((h >> 3) * 256 + c) * 8 + (h & 7)] = f2bf(s);
    } else if (id < 65536) {               // Wf[c][h] = sum_m wv_l[m,c]*wo_l[h,m]
        int id2 = id - 32768;
        int c = id2 >> 7, h = id2 & 127;
        float s = 0.f;
        for (int m = 0; m < 128; ++m) s = fmaf(wv_l[m * 256 + c], wo_l[h * 128 + m], s);
        wfpk[((c >> 3) * 128 + h) * 8 + (c & 7)] = f2bf(s);
    } else if (id < 65792) {               // a0[c] = sum_m wk_l[m,c]*bq_l[m]
        int c = id - 65536;
        float s = 0.f;
        for (int m = 0; m < 128; ++m) s = fmaf(wk_l[m * 256 + c], bq_l[m], s);
        ws[WS_A0 + c] = s;
    } else if (id < 65920) {               // u[h] = sum_m bk_l[m]*wq_l[m,h]
        int h = id - 65792;
        float s = 0.f;
        for (int m = 0; m < 128; ++m) s = fmaf(bk_l[m], wq_l[m * 128 + h], s);
        ws[WS_U + h] = s;
    } else if (id < 66048) {               // bf[h] = sum_m bv_l[m]*wo_l[h,m] + bo_l[h]
        int h = id - 65920;
        float s = bo_l[h];
        for (int m = 0; m < 128; ++m) s = fmaf(bv_l[m], wo_l[h * 128 + m], s);
        ws[WS_BF + h] = s;
    } else if (id == 66048) {              // c0 = bq_l . bk_l
        float s = 0.f;
        for (int m = 0; m < 128; ++m) s = fmaf(bq_l[m], bk_l[m], s);
        ws[WS_C0] = s;
    }
}

// ---------- finish pooled mean; derive M_g, c_g, Vo_g ----------
__global__ void k_pool_finish(const float* __restrict__ part,
                              const float* __restrict__ wk_g, const float* __restrict__ wv_g,
                              const float* __restrict__ wq_g, const float* __restrict__ bk_g,
                              const float* __restrict__ bv_g, const float* __restrict__ bq_g,
                              const float* __restrict__ wo_g,
                              float* __restrict__ out_pool, float* __restrict__ ws) {
    __shared__ float pooled[512], kg[512], vg[512];
    int t = threadIdx.x; // 512 threads
    float s = 0.f;
    for (int p = 0; p < POOL_BLOCKS; ++p) s += part[p * 512 + t];
    s *= (1.0f / 50000.0f);
    pooled[t]   = s;
    out_pool[t] = s;
    __syncthreads();
    int j = t >> 7, m = t & 127;
    float k = bk_g[m], v = bv_g[m];
    for (int h = 0; h < 128; ++h) {
        float p = pooled[j * 128 + h];
        k = fmaf(p, wk_g[m * 128 + h], k);
        v = fmaf(p, wv_g[m * 128 + h], v);
    }
    kg[t] = k; vg[t] = v;
    __syncthreads();
    {
        int h2 = t & 127;
        float s2 = 0.f, s3 = 0.f;
        for (int mm = 0; mm < 128; ++mm) {
            s2 = fmaf(wq_g[mm * 128 + h2], kg[j * 128 + mm], s2);
            s3 = fmaf(vg[j * 128 + mm], wo_g[h2 * 128 + mm], s3);
        }
        ws[WS_MG + t]  = s2;
        ws[WS_VOG + t] = s3;
    }
    if (t < 4) {
        float s4 = 0.f;
        for (int mm = 0; mm < 128; ++mm) s4 = fmaf(bq_g[mm], kg[t * 128 + mm], s4);
        ws[WS_CG + t] = s4;
    }
}

// ---------- main fused edge kernel: 32 edges/block, 4 waves ----------
__global__ __launch_bounds__(256)
void k_main(const float* __restrict__ ea, const float* __restrict__ gf,
            const int* __restrict__ eidx, const float* __restrict__ bo_g,
            const float* __restrict__ ws, float* __restrict__ out) {
    __shared__ u16   lds_ea[32 * 128];      // bf16 ea, XOR-swizzled
    __shared__ float lds_qk[32 * 256];      // fp32 qk, XOR-swizzled; reused as bf16 mixed
    __shared__ float lds_Mg[512], lds_Vog[512], lds_u[128], lds_bog[128];
    __shared__ float lds_cg[4], lds_c0[1];
    u16* lds_m = (u16*)lds_qk;

    const int t  = threadIdx.x;
    const int e0 = blockIdx.x * 32;
    const int w = t >> 6, lane = t & 63;
    const int colq = lane & 15, lhi = lane >> 4;

    // ---- stage ea -> bf16 LDS (swizzled): thread covers (row = t>>3, 16 cols) ----
    {
        int row = t >> 3, cc = (t & 7) * 16;
        const float4* src = (const float4*)(ea + (size_t)e0 * 128 + row * 128 + cc);
        float4 v0 = src[0], v1 = src[1], v2 = src[2], v3 = src[3];
        union { u16 h[16]; int4 q[2]; } tmp;
        tmp.h[0] = f2bf(v0.x); tmp.h[1] = f2bf(v0.y); tmp.h[2]  = f2bf(v0.z); tmp.h[3]  = f2bf(v0.w);
        tmp.h[4] = f2bf(v1.x); tmp.h[5] = f2bf(v1.y); tmp.h[6]  = f2bf(v1.z); tmp.h[7]  = f2bf(v1.w);
        tmp.h[8] = f2bf(v2.x); tmp.h[9] = f2bf(v2.y); tmp.h[10] = f2bf(v2.z); tmp.h[11] = f2bf(v2.w);
        tmp.h[12] = f2bf(v3.x); tmp.h[13] = f2bf(v3.y); tmp.h[14] = f2bf(v3.z); tmp.h[15] = f2bf(v3.w);
        int swz = (row & 7) << 3;
        *(int4*)&lds_ea[(row * 128 + cc) ^ swz]     = tmp.q[0];
        *(int4*)&lds_ea[(row * 128 + cc + 8) ^ swz] = tmp.q[1];
    }
    for (int i = t; i < 512; i += 256) { lds_Mg[i] = ws[WS_MG + i]; lds_Vog[i] = ws[WS_VOG + i]; }
    if (t < 128) { lds_u[t] = ws[WS_U + t]; lds_bog[t] = bo_g[t]; }
    if (t < 4)  lds_cg[t] = ws[WS_CG + t];
    if (t == 0) lds_c0[0] = ws[WS_C0];
    __syncthreads();

    // ---- phase A (MFMA): qk[32x256] = ea[32x128] @ At[128x256] + a0 ----
    {
        const short8* atpk = (const short8*)(ws + WS_ATPK);
        f32x4 acc[2][4];
        #pragma unroll
        for (int nt = 0; nt < 4; ++nt) {
            float a0v = ws[WS_A0 + w * 64 + nt * 16 + colq];
            #pragma unroll
            for (int mt = 0; mt < 2; ++mt) acc[mt][nt] = (f32x4){a0v, a0v, a0v, a0v};
        }
        #pragma unroll
        for (int ks = 0; ks < 4; ++ks) {
            short8 afr[2];
            #pragma unroll
            for (int mt = 0; mt < 2; ++mt) {
                int row = mt * 16 + colq;
                afr[mt] = *(const short8*)&lds_ea[(row * 128 + ks * 32 + lhi * 8) ^ ((row & 7) << 3)];
            }
            int chunk = ks * 4 + lhi;
            #pragma unroll
            for (int nt = 0; nt < 4; ++nt) {
                short8 bfr = atpk[chunk * 256 + (w * 64 + nt * 16 + colq)];
                #pragma unroll
                for (int mt = 0; mt < 2; ++mt)
                    acc[mt][nt] = __builtin_amdgcn_mfma_f32_16x16x32_bf16(afr[mt], bfr, acc[mt][nt], 0, 0, 0);
            }
        }
        #pragma unroll
        for (int mt = 0; mt < 2; ++mt)
            #pragma unroll
            for (int nt = 0; nt < 4; ++nt) {
                int c = w * 64 + nt * 16 + colq;
                #pragma unroll
                for (int j = 0; j < 4; ++j) {
                    int row = mt * 16 + lhi * 4 + j;
                    lds_qk[(row * 256 + c) ^ ((row & 7) << 2)] = acc[mt][nt][j];
                }
            }
    }
    __syncthreads();

    // ---- middle: per-wave 8 edges: gather, scores, softmax, mix, global branch ----
    {
        const int eBase = w * 8;
        int i0s[8], i1s[8];
        #pragma unroll
        for (int ee = 0; ee < 8; ++ee) {
            int eG = e0 + eBase + ee;
            i0s[ee] = eidx[eG]; i1s[ee] = eidx[E_EDGES + eG];
        }
        const float c0v = lds_c0[0];
        const float cg0 = lds_cg[0], cg1 = lds_cg[1], cg2 = lds_cg[2], cg3 = lds_cg[3];
        const float2 u2   = *(const float2*)&lds_u[2 * lane];
        const float2 mg0  = *(const float2*)&lds_Mg[2 * lane];
        const float2 mg1  = *(const float2*)&lds_Mg[128 + 2 * lane];
        const float2 mg2  = *(const float2*)&lds_Mg[256 + 2 * lane];
        const float2 mg3  = *(const float2*)&lds_Mg[384 + 2 * lane];
        const float2 bog2 = *(const float2*)&lds_bog[2 * lane];
        const float2 vg0  = *(const float2*)&lds_Vog[2 * lane];
        const float2 vg1  = *(const float2*)&lds_Vog[128 + 2 * lane];
        const float2 vg2  = *(const float2*)&lds_Vog[256 + 2 * lane];
        const float2 vg3  = *(const float2*)&lds_Vog[384 + 2 * lane];

        float2 S[4], Dv[4];
        {
            const float* ps = gf + (size_t)i0s[0] * 512;
            const float* pd = gf + (size_t)i1s[0] * 512;
            #pragma unroll
            for (int s = 0; s < 4; ++s) {
                S[s]  = *(const float2*)(ps + s * 128 + 2 * lane);
                Dv[s] = *(const float2*)(pd + s * 128 + 2 * lane);
            }
        }
        #pragma unroll
        for (int ee = 0; ee < 8; ++ee) {
            int eL = eBase + ee, eG = e0 + eL;
            float2 Sc[4], Dc[4];
            #pragma unroll
            for (int s = 0; s < 4; ++s) { Sc[s] = S[s]; Dc[s] = Dv[s]; }
            if (ee < 7) {   // prefetch next edge's gather
                const float* ps = gf + (size_t)i0s[ee + 1] * 512;
                const float* pd = gf + (size_t)i1s[ee + 1] * 512;
                #pragma unroll
                for (int s = 0; s < 4; ++s) {
                    S[s]  = *(const float2*)(ps + s * 128 + 2 * lane);
                    Dv[s] = *(const float2*)(pd + s * 128 + 2 * lane);
                }
            }
            const int swzf = (eL & 7) << 2, swzh = (eL & 7) << 3;
            float2 qs = *(const float2*)&lds_qk[(eL * 256 + 2 * lane) ^ swzf];
            float2 qd = *(const float2*)&lds_qk[(eL * 256 + 128 + 2 * lane) ^ swzf];
            u32 eau = *(const u32*)&lds_ea[(eL * 128 + 2 * lane) ^ swzh];
            float ea0 = bf2f((u16)(eau & 0xffffu)), ea1 = bf2f((u16)(eau >> 16));

            float pbp = ea0 * u2.x + ea1 * u2.y;
            float p0 = Sc[0].x * qs.x + Sc[0].y * qs.y + Dc[0].x * qd.x + Dc[0].y * qd.y + pbp;
            float p1 = Sc[1].x * qs.x + Sc[1].y * qs.y + Dc[1].x * qd.x + Dc[1].y * qd.y + pbp;
            float p2 = Sc[2].x * qs.x + Sc[2].y * qs.y + Dc[2].x * qd.x + Dc[2].y * qd.y + pbp;
            float p3 = Sc[3].x * qs.x + Sc[3].y * qs.y + Dc[3].x * qd.x + Dc[3].y * qd.y + pbp;
            float g0 = ea0 * mg0.x + ea1 * mg0.y;
            float g1 = ea0 * mg1.x + ea1 * mg1.y;
            float g2 = ea0 * mg2.x + ea1 * mg2.y;
            float g3 = ea0 * mg3.x + ea1 * mg3.y;
            #pragma unroll
            for (int off = 32; off; off >>= 1) {
                p0 += __shfl_xor(p0, off, 64); p1 += __shfl_xor(p1, off, 64);
                p2 += __shfl_xor(p2, off, 64); p3 += __shfl_xor(p3, off, 64);
                g0 += __shfl_xor(g0, off, 64); g1 += __shfl_xor(g1, off, 64);
                g2 += __shfl_xor(g2, off, 64); g3 += __shfl_xor(g3, off, 64);
            }
            float t0 = (p0 + c0v) * SCALE, t1 = (p1 + c0v) * SCALE;
            float t2 = (p2 + c0v) * SCALE, t3 = (p3 + c0v) * SCALE;
            float mx = fmaxf(fmaxf(t0, t1), fmaxf(t2, t3));
            float x0 = __expf(t0 - mx), x1 = __expf(t1 - mx);
            float x2 = __expf(t2 - mx), x3 = __expf(t3 - mx);
            float inv = 1.0f / (x0 + x1 + x2 + x3);
            float a0s = x0 * inv, a1s = x1 * inv, a2s = x2 * inv, a3s = x3 * inv;

            float s0 = (g0 + cg0) * SCALE, s1 = (g1 + cg1) * SCALE;
            float s2 = (g2 + cg2) * SCALE, s3 = (g3 + cg3) * SCALE;
            float mg = fmaxf(fmaxf(s0, s1), fmaxf(s2, s3));
            float y0 = __expf(s0 - mg), y1 = __expf(s1 - mg);
            float y2 = __expf(s2 - mg), y3 = __expf(s3 - mg);
            float invg = 1.0f / (y0 + y1 + y2 + y3);
            float b0 = y0 * invg, b1 = y1 * invg, b2 = y2 * invg, b3 = y3 * invg;

            size_t ro = (size_t)eG * 384;
            if (lane < 4)
                out[OUT_GAW + (size_t)eG * 4 + lane] =
                    (lane == 0) ? b0 : (lane == 1) ? b1 : (lane == 2) ? b2 : b3;

            float2 go;
            go.x = bog2.x + b0 * vg0.x + b1 * vg1.x + b2 * vg2.x + b3 * vg3.x;
            go.y = bog2.y + b0 * vg0.y + b1 * vg1.y + b2 * vg2.y + b3 * vg3.y;
            *(float2*)(out + ro + 256 + 2 * lane) = go;

            float2 pth = *(const float2*)(ea + (size_t)eG * 128 + 2 * lane);  // exact passthrough
            *(float2*)(out + ro + 2 * lane) = pth;

            // mixed -> bf16 into the qk buffer (this wave's row only)
            // logical channels must be CONTIGUOUS [0,256) per row for phase B:
            //   src-half at off = 2*lane, dst-half at off = 128 + 2*lane.
            float msx = a0s * Sc[0].x + a1s * Sc[1].x + a2s * Sc[2].x + a3s * Sc[3].x;
            float msy = a0s * Sc[0].y + a1s * Sc[1].y + a2s * Sc[2].y + a3s * Sc[3].y;
            float mdx = a0s * Dc[0].x + a1s * Dc[1].x + a2s * Dc[2].x + a3s * Dc[3].x;
            float mdy = a0s * Dc[0].y + a1s * Dc[1].y + a2s * Dc[2].y + a3s * Dc[3].y;
            u32 pks = (u32)f2bf(msx) | ((u32)f2bf(msy) << 16);
            u32 pkd = (u32)f2bf(mdx) | ((u32)f2bf(mdy) << 16);
            *(u32*)&lds_m[(eL * 512 + 2 * lane) ^ swzh]       = pks;
            *(u32*)&lds_m[(eL * 512 + 128 + 2 * lane) ^ swzh] = pkd;
        }
    }
    __syncthreads();

    // ---- phase B (MFMA): local_out[32x128] = mixed[32x256] @ Wf[256x128] + bf ----
    {
        const short8* wfpk = (const short8*)(ws + WS_WFPK);
        f32x4 acc[2][2];
        #pragma unroll
        for (int nt = 0; nt < 2; ++nt) {
            float bfv = ws[WS_BF + w * 32 + nt * 16 + colq];
            #pragma unroll
            for (int mt = 0; mt < 2; ++mt) acc[mt][nt] = (f32x4){bfv, bfv, bfv, bfv};
        }
        #pragma unroll
        for (int ks = 0; ks < 8; ++ks) {
            short8 afr[2];
            #pragma unroll
            for (int mt = 0; mt < 2; ++mt) {
                int row = mt * 16 + colq;
                afr[mt] = *(const short8*)&lds_m[(row * 512 + ks * 32 + lhi * 8) ^ ((row & 7) << 3)];
            }
            int chunk = ks * 4 + lhi;
            #pragma unroll
            for (int nt = 0; nt < 2; ++nt) {
                short8 bfr = wfpk[chunk * 128 + (w * 32 + nt * 16 + colq)];
                #pragma unroll
                for (int mt = 0; mt < 2; ++mt)
                    acc[mt][nt] = __builtin_amdgcn_mfma_f32_16x16x32_bf16(afr[mt], bfr, acc[mt][nt], 0, 0, 0);
            }
        }
        #pragma unroll
        for (int mt = 0; mt < 2; ++mt)
            #pragma unroll
            for (int nt = 0; nt < 2; ++nt) {
                int c = w * 32 + nt * 16 + colq;
                #pragma unroll
                for (int j = 0; j < 4; ++j) {
                    int row = mt * 16 + lhi * 4 + j;
                    out[(size_t)(e0 + row) * 384 + 128 + c] = acc[mt][nt][j];
                }
            }
    }
}

extern "C" void kernel_launch(void* const* d_in, const int* in_sizes, int n_in,
                              void* d_out, int out_size, void* d_ws, size_t ws_size,
                              hipStream_t stream) {
    const float* edge_attr = (const float*)d_in[0];
    const float* gf        = (const float*)d_in[1];
    const int*   eidx      = (const int*)d_in[2];
    const float* wq_l = (const float*)d_in[3];
    const float* wk_l = (const float*)d_in[4];
    const float* wv_l = (const float*)d_in[5];
    const float* bq_l = (const float*)d_in[6];
    const float* bk_l = (const float*)d_in[7];
    const float* bv_l = (const float*)d_in[8];
    const float* wo_l = (const float*)d_in[9];
    const float* bo_l = (const float*)d_in[10];
    const float* wq_g = (const float*)d_in[11];
    const float* wk_g = (const float*)d_in[12];
    const float* wv_g = (const float*)d_in[13];
    const float* bq_g = (const float*)d_in[14];
    const float* bk_g = (const float*)d_in[15];
    const float* bv_g = (const float*)d_in[16];
    const float* wo_g = (const float*)d_in[17];
    const float* bo_g = (const float*)d_in[18];

    float* out = (float*)d_out;
    float* ws  = (float*)d_ws;

    k_pool_partial<<<POOL_BLOCKS, 256, 0, stream>>>(gf, ws + WS_PART);
    k_prep_w<<<259, 256, 0, stream>>>(wq_l, wk_l, wv_l, bq_l, bk_l, bv_l, wo_l, bo_l, ws);
    k_pool_finish<<<1, 512, 0, stream>>>(ws + WS_PART, wk_g, wv_g, wq_g, bk_g, bv_g, bq_g, wo_g,
                                         out + OUT_POOL, ws);
    k_main<<<E_EDGES / 32, 256, 0, stream>>>(edge_attr, gf, eidx, bo_g, ws, out);
}